// Round 4
// baseline (398.835 us; speedup 1.0000x reference)
//
#include <hip/hip_runtime.h>
#include <stdint.h>

typedef int v4i   __attribute__((ext_vector_type(4)));
typedef int v16i  __attribute__((ext_vector_type(16)));

#define B_    128
#define C_    64
#define H_    56
#define W_    56
#define HW_   3136
#define NELEM (B_*C_*HW_)          // 25,690,112

// int8 tensors use the g-split layout [n][y][g=ci/16][x][16] so conv staging
// and A-fragment LDS reads are contiguous-per-lane (bank-conflict-free).
#define OFF_K0   0
#define OFF_K1   ((size_t)NELEM)
#define OFF_WB   ((size_t)2*NELEM)                  // int8 [2][g=4][s=9][co=64][16]
#define OFF_PAR  (OFF_WB + 2*4*9*64*16)             // float qw[128], qb[128], aqlut[1024]; double Kd[128]
#define OFF_MAX  (OFF_PAR + 6144)                   // uint32 absmax bits

// ---------------------------------------------------------------- absmax(x)
__global__ void k_absmax(const float* __restrict__ x, unsigned* __restrict__ maxbits) {
    __shared__ float smax[4];
    float m = 0.f;
    const int n4 = NELEM / 4;
    for (int i = blockIdx.x * blockDim.x + threadIdx.x; i < n4; i += gridDim.x * blockDim.x) {
        float4 v = ((const float4*)x)[i];
        m = fmaxf(m, fmaxf(fmaxf(fabsf(v.x), fabsf(v.y)), fmaxf(fabsf(v.z), fabsf(v.w))));
    }
    for (int off = 32; off; off >>= 1) m = fmaxf(m, __shfl_down(m, off, 64));
    if ((threadIdx.x & 63) == 0) smax[threadIdx.x >> 6] = m;
    __syncthreads();
    if (threadIdx.x == 0) {
        float mm = fmaxf(fmaxf(smax[0], smax[1]), fmaxf(smax[2], smax[3]));
        atomicMax(maxbits, __float_as_uint(mm));   // nonneg: uint order == float order
    }
}

// ------------------------------------- quantize x -> int8 k, g-split layout
__global__ void k_quant(const float* __restrict__ x, const unsigned* __restrict__ maxbits,
                        int8_t* __restrict__ k8) {
    __shared__ __align__(16) int8_t tile[W_ * C_];   // [x][c]
    const int n = blockIdx.x / H_;
    const int y = blockIdx.x % H_;
    const float T = fminf(fmaxf(__uint_as_float(*maxbits), 1e-10f), 255.0f);
    for (int i = threadIdx.x; i < C_ * 14; i += blockDim.x) {
        int c = i / 14, j = i % 14;
        float4 v = *(const float4*)(x + ((size_t)(n * C_ + c)) * HW_ + y * W_ + j * 4);
        float vv[4] = {v.x, v.y, v.z, v.w};
#pragma unroll
        for (int q = 0; q < 4; q++) {
            float t = fminf(fmaxf(vv[q], -T), T);
            float u = __fdiv_rn(t, T);
            int k = (int)rintf(__fmul_rn(u, 7.0f));
            tile[(j * 4 + q) * C_ + c] = (int8_t)k;
        }
    }
    __syncthreads();
    if (threadIdx.x < 224) {
        int g = threadIdx.x / 56, xx = threadIdx.x % 56;
        *(int4*)(k8 + ((((size_t)(n * 56 + y)) * 4 + g) * 56 + xx) * 16) =
            *(const int4*)(tile + xx * 64 + g * 16);
    }
}

// --------------------------- weight binarization, numpy-pairwise-faithful f32
__device__ __forceinline__ float pw_reduce64(float r) {
    r = __fadd_rn(r, __shfl_xor(r, 1, 64));
    r = __fadd_rn(r, __shfl_xor(r, 2, 64));
    r = __fadd_rn(r, __shfl_xor(r, 4, 64));
    r = __fadd_rn(r, __shfl_xor(r, 8, 64));
    r = __fadd_rn(r, __shfl_xor(r, 16, 64));
    r = __fadd_rn(r, __shfl_xor(r, 32, 64));
    return r;
}

__global__ void k_prepw(const float* __restrict__ w1, const float* __restrict__ w2,
                        int8_t* __restrict__ wb, float* __restrict__ par) {
    const int layer = blockIdx.x >> 6;
    const int co    = blockIdx.x & 63;
    const float* w = (layer ? w2 : w1) + (size_t)co * 576;
    const int lane = threadIdx.x;
    const int base = (lane >> 3) * 72 + (lane & 7);

    float v[9];
#pragma unroll
    for (int i = 0; i < 9; i++) v[i] = w[base + 8 * i];

    float s = v[0];
#pragma unroll
    for (int i = 1; i < 9; i++) s = __fadd_rn(s, v[i]);
    const float mean = __fdiv_rn(pw_reduce64(s), 576.0f);

    float d0 = __fsub_rn(v[0], mean);
    float sq = __fmul_rn(d0, d0);
#pragma unroll
    for (int i = 1; i < 9; i++) {
        float d = __fsub_rn(v[i], mean);
        sq = __fadd_rn(sq, __fmul_rn(d, d));
    }
    const float sig = __fsqrt_rn(__fdiv_rn(pw_reduce64(sq), 575.0f));

    float sa = fabsf(__fdiv_rn(__fsub_rn(v[0], mean), sig));
#pragma unroll
    for (int i = 1; i < 9; i++)
        sa = __fadd_rn(sa, fabsf(__fdiv_rn(__fsub_rn(v[i], mean), sig)));
    const float ma = __fdiv_rn(pw_reduce64(sa), 576.0f);
    const float p  = rintf(log2f(ma));
    if (lane == 0)
        ((double*)(par + 1280))[layer * 64 + co] = exp2((double)p) * (341.0 / 1344.0);

#pragma unroll
    for (int i = 0; i < 9; i++) {
        int ig = base + 8 * i;
        float d = __fsub_rn(v[i], mean);
        int8_t sg = (d > 0.0f) ? (int8_t)1 : ((d < 0.0f) ? (int8_t)-1 : (int8_t)0);
        int ci = ig / 9, t = ig % 9;
        wb[((((size_t)layer * 4 + (ci >> 4)) * 9 + t) * 64 + co) * 16 + (ci & 15)] = sg;
    }
}

// -------------------------------- BN affine + aq LUT
__global__ void k_prepbn(const float* g1, const float* bb1, const float* mm1, const float* vv1,
                         const float* g2, const float* bb2, const float* mm2, const float* vv2,
                         float* __restrict__ par) {
    const int tid = threadIdx.x;
    if (tid < 128) {
        const int layer = tid >> 6;
        const int c = tid & 63;
        const float* g  = layer ? g2  : g1;
        const float* be = layer ? bb2 : bb1;
        const float* mu = layer ? mm2 : mm1;
        const float* va = layer ? vv2 : vv1;
        const float stdv = __fsqrt_rn(__fadd_rn(va[c], 1e-5f));
        const float w = __fdiv_rn(g[c], stdv);
        const float b = __fsub_rn(be[c], __fmul_rn(w, mu[c]));
        float aw = fabsf(w), ab = fabsf(b);
        for (int off = 32; off; off >>= 1) {
            aw = fmaxf(aw, __shfl_xor(aw, off, 64));
            ab = fmaxf(ab, __shfl_xor(ab, off, 64));
        }
        const float Tw = fminf(fmaxf(aw, 1e-10f), 255.0f);
        const float Tb = fminf(fmaxf(ab, 1e-10f), 255.0f);
        {
            float vq = __fdiv_rn(fminf(fmaxf(w, -Tw), Tw), Tw);
            float r  = rintf(__fmul_rn(vq, 7.0f));
            float qf = __fadd_rn(vq, __fsub_rn(__fdiv_rn(r, 7.0f), vq));
            par[layer * 64 + c] = __fmul_rn(qf, Tw);
        }
        {
            float vq = __fdiv_rn(fminf(fmaxf(b, -Tb), Tb), Tb);
            float r  = rintf(__fmul_rn(vq, 4095.0f));
            float qf = __fadd_rn(vq, __fsub_rn(__fdiv_rn(r, 4095.0f), vq));
            par[128 + layer * 64 + c] = __fmul_rn(qf, Tb);
        }
    }
    // aq LUT: aq(rr) = fmul(fdiv(rr,1023),576)  (== ref chain; y1==q1 by Sterbenz)
    for (int i = tid; i < 1024; i += blockDim.x)
        par[256 + i] = __fmul_rn(__fdiv_rn((float)i, 1023.0f), 576.0f);
}

// ------------------------------------------------ fused conv + BN + residual
// grid: B*14 blocks; block = (n, 4 rows) -> M=224 (pad 256), N=64.
// LDS g-split layouts: A/B reads are lane-contiguous 16B (conflict-free).
template <int LAYER>
__global__ __launch_bounds__(256) void k_conv(const int8_t* __restrict__ kin,
                                              const int8_t* __restrict__ wb,
                                              const float* __restrict__ par,
                                              int8_t* __restrict__ kout,
                                              float* __restrict__ fout) {
    constexpr int OUTB = (LAYER == 2) ? 57600 : 36864;     // out2 (pitch 225) overlays wsm
    __shared__ __align__(16) int8_t smem[22272 + OUTB + 64];
    int8_t* halo = smem;                       // [g=4][r=6][x=58][16]
    int8_t* wsm  = smem + 22272;               // [g=4][s=9][co=64][16]
    float*  out2 = (float*)(smem + 22272);     // [co][pitch 225] (LAYER 2)
    float*  xqlut = (float*)(smem + 22272 + OUTB);

    const int n  = blockIdx.x / 14;
    const int y0 = (blockIdx.x % 14) * 4;
    const int tid = threadIdx.x;

    for (int u = tid; u < 1392; u += 256) {            // halo: 4g x 6r x 58x
        int xx = u % 58, gr = u / 58;
        int g = gr / 6, r = gr % 6;
        int y = y0 - 1 + r, xg = xx - 1;
        int4 val = {0, 0, 0, 0};
        if (y >= 0 && y < 56 && xg >= 0 && xg < 56)
            val = *(const int4*)(kin + ((((size_t)(n * 56 + y)) * 4 + g) * 56 + xg) * 16);
        *(int4*)(halo + ((g * 6 + r) * 58 + xx) * 16) = val;
    }
    const int8_t* wsrc = wb + (size_t)(LAYER - 1) * 36864;
    for (int u = tid; u < 2304; u += 256)
        *(int4*)(wsm + u * 16) = *(const int4*)(wsrc + u * 16);
    if (tid < 15) xqlut[tid] = __fdiv_rn((float)(tid - 7), 7.0f);
    __syncthreads();

    const int wv = tid >> 6, lane = tid & 63;
    const int ml = lane & 31, khalf = lane >> 5;
    const int wvbase = wv * 64;

    int rmT[2], cmT[2];
#pragma unroll
    for (int T = 0; T < 2; T++) {
        int m = wvbase + T * 32 + ml;
        if (m > 223) m = 223;
        int q = (m * 586) >> 15;                 // m/56 for m<224
        rmT[T] = q; cmT[T] = m - q * 56;
    }

    v16i acc[2][2];
#pragma unroll
    for (int a = 0; a < 2; a++)
#pragma unroll
        for (int b = 0; b < 2; b++)
#pragma unroll
            for (int i = 0; i < 16; i++) acc[a][b][i] = 0;

#pragma unroll
    for (int s = 0; s < 9; s++) {
        const int ky = s / 3, kx = s % 3;
#pragma unroll
        for (int kb = 0; kb < 2; kb++) {
            const int g = kb * 2 + khalf;
            v4i a0 = *(const v4i*)(halo + ((g * 6 + rmT[0] + ky) * 58 + cmT[0] + kx) * 16);
            v4i a1 = *(const v4i*)(halo + ((g * 6 + rmT[1] + ky) * 58 + cmT[1] + kx) * 16);
            v4i b0 = *(const v4i*)(wsm + ((g * 9 + s) * 64 + ml) * 16);
            v4i b1 = *(const v4i*)(wsm + ((g * 9 + s) * 64 + ml + 32) * 16);
            acc[0][0] = __builtin_amdgcn_mfma_i32_32x32x32_i8(a0, b0, acc[0][0], 0, 0, 0);
            acc[0][1] = __builtin_amdgcn_mfma_i32_32x32x32_i8(a0, b1, acc[0][1], 0, 0, 0);
            acc[1][0] = __builtin_amdgcn_mfma_i32_32x32x32_i8(a1, b0, acc[1][0], 0, 0, 0);
            acc[1][1] = __builtin_amdgcn_mfma_i32_32x32x32_i8(a1, b1, acc[1][1], 0, 0, 0);
        }
    }

    if (LAYER == 2) __syncthreads();   // out2 overlays wsm; wait for all K-loops

    const float* qw  = par + (LAYER - 1) * 64;
    const float* qb  = par + 128 + (LAYER - 1) * 64;
    const float* aql = par + 256;
    const double* Kd = (const double*)(par + 1280) + (LAYER - 1) * 64;

#pragma unroll
    for (int t = 0; t < 2; t++) {
        const int co = ml + 32 * t;
        const float qwf = qw[co], qbf = qb[co];
        const double Kc = Kd[co];
        const int hbase = (co >> 4) * 6;       // halo g row-base
#pragma unroll
        for (int T = 0; T < 2; T++) {
#pragma unroll
            for (int r = 0; r < 16; r++) {
                const int mrow = wvbase + T * 32 + 4 * khalf + (r & 3) + 8 * (r >> 2);
                if (mrow > 223) continue;
                const int S = acc[T][t][r];
                const int rri = (int)rint((double)S * Kc);       // exact requant decision
                const int idx = rri < 0 ? -rri : rri;
                float aqa = (idx <= 1023) ? aql[idx]
                          : __fmul_rn(__fdiv_rn((float)idx, 1023.0f), 576.0f);
                const float aq = rri < 0 ? -aqa : aqa;
                const int rloc = (mrow * 586) >> 15;
                const int cloc = mrow - rloc * 56;
                const int kc = (int)halo[((hbase + rloc + 1) * 58 + cloc + 1) * 16 + (co & 15)];
                const float xq = xqlut[kc + 7];
                float val = __fadd_rn(__fadd_rn(__fmul_rn(aq, qwf), qbf), xq);
                val = fminf(fmaxf(val, -1.0f), 1.0f);            // hardtanh
                if (LAYER == 1) {
                    const int k2 = (int)rintf(__fmul_rn(val, 7.0f));   // T1 == 1.0
                    const int y = y0 + rloc;
                    kout[((((size_t)(n * 56 + y)) * 4 + (co >> 4)) * 56 + cloc) * 16 + (co & 15)]
                        = (int8_t)k2;
                } else {
                    out2[co * 225 + mrow] = val;
                }
            }
        }
    }

    if (LAYER == 2) {
        __syncthreads();
        float* dst = fout + (size_t)n * 64 * HW_ + (size_t)y0 * 56;
        for (int it = 0; it < 56; it++) {
            int u = it * 256 + tid;
            int co = u / 224, m = u - co * 224;
            dst[(size_t)co * HW_ + m] = out2[co * 225 + m];
        }
    }
}

// ----------------------------------------------------------------- launcher
extern "C" void kernel_launch(void* const* d_in, const int* in_sizes, int n_in,
                              void* d_out, int out_size, void* d_ws, size_t ws_size,
                              hipStream_t stream) {
    const float* x  = (const float*)d_in[0];
    const float* w1 = (const float*)d_in[1];
    const float* w2 = (const float*)d_in[2];
    const float* g1 = (const float*)d_in[3];
    const float* b1 = (const float*)d_in[4];
    const float* m1 = (const float*)d_in[5];
    const float* v1 = (const float*)d_in[6];
    const float* g2 = (const float*)d_in[7];
    const float* b2 = (const float*)d_in[8];
    const float* m2 = (const float*)d_in[9];
    const float* v2 = (const float*)d_in[10];

    char* ws = (char*)d_ws;
    int8_t*  k0  = (int8_t*)(ws + OFF_K0);
    int8_t*  k1  = (int8_t*)(ws + OFF_K1);
    int8_t*  wbp = (int8_t*)(ws + OFF_WB);
    float*   par = (float*)(ws + OFF_PAR);
    unsigned* mx = (unsigned*)(ws + OFF_MAX);

    hipMemsetAsync(mx, 0, 4, stream);
    k_absmax<<<1024, 256, 0, stream>>>(x, mx);
    k_quant<<<B_ * H_, 256, 0, stream>>>(x, mx, k0);
    k_prepw<<<128, 64, 0, stream>>>(w1, w2, wbp, par);
    k_prepbn<<<1, 256, 0, stream>>>(g1, b1, m1, v1, g2, b2, m2, v2, par);
    k_conv<1><<<B_ * 14, 256, 0, stream>>>(k0, wbp, par, k1, nullptr);
    k_conv<2><<<B_ * 14, 256, 0, stream>>>(k1, wbp, par, nullptr, (float*)d_out);
}